// Round 11
// baseline (1015.602 us; speedup 1.0000x reference)
//
#include <hip/hip_runtime.h>
#include <math.h>

typedef _Float16 h8_t __attribute__((ext_vector_type(8)));
typedef _Float16 h4_t __attribute__((ext_vector_type(4)));
typedef float f4_t __attribute__((ext_vector_type(4)));

// LDS tiles: [R][32] halfs (64 B rows) with a 16B-slot XOR swizzle:
// logical chunk g (0..3) of row r is stored at slot s = g ^ ((r>>1)&3).
// Fixes the 8-way ds_read_b128 bank conflict (measured 1.47e7) down to
// 2-way (free). B is staged via global_load_lds with PRE-SWIZZLED source
// (rule #21: linear dest + inverse-permuted source + swizzled read); the
// permutation stays inside one 64 B cacheline -> no coalescing loss.

__device__ __forceinline__ int swz(int row, int fq) {
  return fq ^ (((row >> 1) & 3) << 3);   // fq in halfs (0,8,16,24)
}

// fast sigmoid / tanh using native v_exp_f32 + v_rcp_f32.
__device__ __forceinline__ float fsig(float x) {
  return __builtin_amdgcn_rcpf(1.f + __expf(-x));
}
__device__ __forceinline__ float ftanh(float x) {
  float e = __expf(-2.f * fabsf(x));
  float t = (1.f - e) * __builtin_amdgcn_rcpf(1.f + e);
  return copysignf(t, x);
}

// XCD-aware bijective block swizzle (T1).
__device__ __forceinline__ int xcd_swz_lin(int lin, int nwg) {
  if (nwg & 7) return lin;
  int cpx = nwg >> 3;
  return (lin & 7) * cpx + (lin >> 3);
}

// async global->LDS, 16 B per lane (dest = wave-uniform base + lane*16).
__device__ __forceinline__ void gload16(const _Float16* g, _Float16* l) {
  __builtin_amdgcn_global_load_lds(
      (const __attribute__((address_space(1))) void*)g,
      (__attribute__((address_space(3))) void*)l, 16, 0, 0);
}

// stage R rows x 32 halfs from f16 source into swizzled LDS [R][32].
// LDS dest linear (idx*16 B = row*64 + s*16, s=idx&3); source chunk is
// g = s ^ ((row>>1)&3) so that logical chunk g lands at slot s.
template <int R>
__device__ __forceinline__ void gstage(const _Float16* __restrict__ src, int ld,
                                       _Float16* __restrict__ dst, int t) {
#pragma unroll
  for (int it = 0; it < R / 64; ++it) {
    int idx = t + it * 256;       // 0..R*4-1
    int row = idx >> 2;           // 0..R-1
    int sl  = idx & 3;            // phys slot
    int kq  = (sl ^ ((row >> 1) & 3)) << 3;   // logical chunk, halfs
    gload16(src + (size_t)row * ld + kq, dst + (size_t)idx * 8);
  }
}

// T14 reg-staged fp32 A-path: loadA issues float4 loads to regs; writeA
// cvt+ds_write into swizzled LDS. Write pattern still covers a full
// contiguous-permuted 512 B per wave -> conflict-free.
template <int R>
__device__ __forceinline__ void loadA_f32(const float* __restrict__ src, int ld,
                                          int t, float4* v) {
#pragma unroll
  for (int it = 0; it < R / 32; ++it) {
    int idx = t + it * 256;       // 0..R*8-1
    int row = idx >> 3;           // 0..R-1
    int kg  = (idx & 7) << 2;     // 0,4,..,28
    v[it] = *(const float4*)(src + (size_t)row * ld + kg);
  }
}
template <int R>
__device__ __forceinline__ void writeA_f16(_Float16* __restrict__ dst, int t,
                                           const float4* v) {
#pragma unroll
  for (int it = 0; it < R / 32; ++it) {
    int idx = t + it * 256;
    int row = idx >> 3;
    int c   = idx & 7;            // 8-B chunk index
    int g   = c >> 1, h = c & 1;
    int sl  = g ^ ((row >> 1) & 3);
    h4_t hv = {(_Float16)v[it].x, (_Float16)v[it].y,
               (_Float16)v[it].z, (_Float16)v[it].w};
    *(h4_t*)(dst + row * 32 + sl * 8 + h * 4) = hv;
  }
}

// Convert the 4 weight matrices fp32 -> f16 (one launch)
__global__ __launch_bounds__(256) void convert_weights(
    const float* __restrict__ Wioux, const float* __restrict__ Wiouh,
    const float* __restrict__ Wfx, const float* __restrict__ Wfh,
    _Float16* __restrict__ Wx, _Float16* __restrict__ Wh,
    _Float16* __restrict__ Wfxh, _Float16* __restrict__ Wfhh)
{
  int i4 = (blockIdx.x * 256 + threadIdx.x) * 4;   // < 786432
  const float* src; _Float16* dst; int off;
  if (i4 < 393216)      { src = Wioux; dst = Wx;   off = i4; }
  else if (i4 < 589824) { src = Wiouh; dst = Wh;   off = i4 - 393216; }
  else if (i4 < 720896) { src = Wfx;   dst = Wfxh; off = i4 - 589824; }
  else                  { src = Wfh;   dst = Wfhh; off = i4 - 720896; }
  float4 v = *(const float4*)(src + off);
  h4_t h = {(_Float16)v.x, (_Float16)v.y, (_Float16)v.z, (_Float16)v.w};
  *(h4_t*)(dst + off) = h;
}

// fx = x @ Wfx.T (rows = 73*256), fp32 out. 64-row x 256-col tile,
// single-barrier double-buffered K-loop: stage next (A ds_write + B DMA)
// BEFORE computing current; the barrier's vmcnt drain lands after the
// MFMA window instead of before it.
__global__ __launch_bounds__(256) void fx_gemm(
    const float* __restrict__ x, const _Float16* __restrict__ Wfx,
    float* __restrict__ out)
{
  __shared__ _Float16 As[2][64 * 32];
  __shared__ _Float16 Bs[2][256 * 32];
  const int t = threadIdx.x;
  int swzb = xcd_swz_lin(blockIdx.x, gridDim.x);
  const int r0 = swzb * 64;
  const int w = t >> 6, lane = t & 63;
  const int wr = (w >> 1) * 32, wc = (w & 1) * 128;
  const int fr = lane & 15, fq = (lane >> 4) * 8;
  f4_t acc[2][8] = {};
  float4 va[2];
  loadA_f32<64>(x + (size_t)r0 * 512, 512, t, va);
  writeA_f16<64>(As[0], t, va);
  gstage<256>(Wfx, 512, Bs[0], t);
  loadA_f32<64>(x + (size_t)r0 * 512 + 32, 512, t, va);
  __syncthreads();
  int cur = 0;
  for (int k0 = 0; k0 < 512; k0 += 32) {
    int nxt = cur ^ 1;
    if (k0 + 32 < 512) {
      writeA_f16<64>(As[nxt], t, va);
      gstage<256>(Wfx + (size_t)(k0 + 32), 512, Bs[nxt], t);
      if (k0 + 64 < 512)
        loadA_f32<64>(x + (size_t)r0 * 512 + k0 + 64, 512, t, va);
    }
    h8_t a[2], b[8];
#pragma unroll
    for (int rt = 0; rt < 2; ++rt) {
      int row = wr + rt * 16 + fr;
      a[rt] = *(const h8_t*)(As[cur] + row * 32 + swz(row, fq));
    }
#pragma unroll
    for (int ct = 0; ct < 8; ++ct) {
      int row = wc + ct * 16 + fr;
      b[ct] = *(const h8_t*)(Bs[cur] + row * 32 + swz(row, fq));
    }
#pragma unroll
    for (int rt = 0; rt < 2; ++rt)
#pragma unroll
      for (int ct = 0; ct < 8; ++ct)
        acc[rt][ct] = __builtin_amdgcn_mfma_f32_16x16x32_f16(a[rt], b[ct], acc[rt][ct], 0, 0, 0);
    __syncthreads();
    cur = nxt;
  }
#pragma unroll
  for (int rt = 0; rt < 2; ++rt)
#pragma unroll
    for (int ct = 0; ct < 8; ++ct)
#pragma unroll
      for (int i = 0; i < 4; ++i) {
        int row = wr + rt * 16 + (lane >> 4) * 4 + i;
        int col = wc + ct * 16 + (lane & 15);
        out[(size_t)(r0 + row) * 256 + col] = acc[rt][ct][i];
      }
}

// fh = h @ Wfh.T (rows = L*256), f16 out. Same dbuf + swizzle structure.
__global__ __launch_bounds__(256) void fh_gemm(
    const float* __restrict__ h_src, const _Float16* __restrict__ Wfh,
    _Float16* __restrict__ out)
{
  __shared__ _Float16 As[2][64 * 32];
  __shared__ _Float16 Bs[2][256 * 32];
  const int t = threadIdx.x;
  int swzb = xcd_swz_lin(blockIdx.x, gridDim.x);
  const int r0 = swzb * 64;
  const int w = t >> 6, lane = t & 63;
  const int wr = (w >> 1) * 32, wc = (w & 1) * 128;
  const int fr = lane & 15, fq = (lane >> 4) * 8;
  f4_t acc[2][8] = {};
  float4 va[2];
  loadA_f32<64>(h_src + (size_t)r0 * 256, 256, t, va);
  writeA_f16<64>(As[0], t, va);
  gstage<256>(Wfh, 256, Bs[0], t);
  loadA_f32<64>(h_src + (size_t)r0 * 256 + 32, 256, t, va);
  __syncthreads();
  int cur = 0;
  for (int k0 = 0; k0 < 256; k0 += 32) {
    int nxt = cur ^ 1;
    if (k0 + 32 < 256) {
      writeA_f16<64>(As[nxt], t, va);
      gstage<256>(Wfh + (size_t)(k0 + 32), 256, Bs[nxt], t);
      if (k0 + 64 < 256)
        loadA_f32<64>(h_src + (size_t)r0 * 256 + k0 + 64, 256, t, va);
    }
    h8_t a[2], b[8];
#pragma unroll
    for (int rt = 0; rt < 2; ++rt) {
      int row = wr + rt * 16 + fr;
      a[rt] = *(const h8_t*)(As[cur] + row * 32 + swz(row, fq));
    }
#pragma unroll
    for (int ct = 0; ct < 8; ++ct) {
      int row = wc + ct * 16 + fr;
      b[ct] = *(const h8_t*)(Bs[cur] + row * 32 + swz(row, fq));
    }
#pragma unroll
    for (int rt = 0; rt < 2; ++rt)
#pragma unroll
      for (int ct = 0; ct < 8; ++ct)
        acc[rt][ct] = __builtin_amdgcn_mfma_f32_16x16x32_f16(a[rt], b[ct], acc[rt][ct], 0, 0, 0);
    __syncthreads();
    cur = nxt;
  }
#pragma unroll
  for (int rt = 0; rt < 2; ++rt)
#pragma unroll
    for (int ct = 0; ct < 8; ++ct)
#pragma unroll
      for (int i = 0; i < 4; ++i) {
        int row = wr + rt * 16 + (lane >> 4) * 4 + i;
        int col = wc + ct * 16 + (lane & 15);
        out[(size_t)(r0 + row) * 256 + col] = (_Float16)acc[rt][ct][i];
      }
}

// Fused: chs = f16(sum_j w_j h[child_j]) AND
// cacc = sum_j sigmoid(w_j*fh[child_j] + bfh + bfx + fx) * w_j * c[child_j]
__global__ __launch_bounds__(256) void chs_fgate(
    const float* __restrict__ h_all, const _Float16* __restrict__ fh,
    const _Float16* __restrict__ c_half, const float* __restrict__ prob,
    const float* __restrict__ bfh, const float* __restrict__ bfx,
    const float* __restrict__ fxb, _Float16* __restrict__ chs,
    float* __restrict__ cacc, int s, int cs)
{
  int blk = xcd_swz_lin(blockIdx.x, gridDim.x);
  int idx = blk * 256 + threadIdx.x;   // over L*16384
  int m = (idx & 63) << 2;
  int b = (idx >> 6) & 255;
  int nl = idx >> 14;
  int node = s + nl;
  float4 vfx = *(const float4*)(fxb + ((size_t)node * 256 + b) * 256 + m);
  float4 vbh = *(const float4*)(bfh + m);
  float4 vbx = *(const float4*)(bfx + m);
  float b0 = vfx.x + vbh.x + vbx.x;
  float b1 = vfx.y + vbh.y + vbx.y;
  float b2 = vfx.z + vbh.z + vbx.z;
  float b3 = vfx.w + vbh.w + vbx.w;
  float4 hacc = {0.f, 0.f, 0.f, 0.f};
  float4 cc = {0.f, 0.f, 0.f, 0.f};
#pragma unroll
  for (int j = 0; j < 8; ++j) {
    int child = node * 8 + 1 + j;
    float wv = prob[node * 585 + child];
    float4 hv = *(const float4*)(h_all + (size_t)child * 65536 + b * 256 + m);
    hacc.x += wv * hv.x; hacc.y += wv * hv.y;
    hacc.z += wv * hv.z; hacc.w += wv * hv.w;
    h4_t fv = *(const h4_t*)(fh + (size_t)(child - cs) * 65536 + b * 256 + m);
    h4_t cv = *(const h4_t*)(c_half + (size_t)child * 65536 + b * 256 + m);
    cc.x += wv * (float)cv[0] * fsig(wv * (float)fv[0] + b0);
    cc.y += wv * (float)cv[1] * fsig(wv * (float)fv[1] + b1);
    cc.z += wv * (float)cv[2] * fsig(wv * (float)fv[2] + b2);
    cc.w += wv * (float)cv[3] * fsig(wv * (float)fv[3] + b3);
  }
  h4_t hc = {(_Float16)hacc.x, (_Float16)hacc.y, (_Float16)hacc.z, (_Float16)hacc.w};
  *(h4_t*)(chs + (size_t)nl * 65536 + b * 256 + m) = hc;
  *(float4*)(cacc + ((size_t)nl * 256 + b) * 256 + m) = cc;
}

// Fused iou GEMM + pointwise, 64 rows x (CT*32) m-cols x 3 gates.
// Single-barrier double-buffered K-loop + swizzled LDS.
template <int CT>
__global__ __launch_bounds__(256) void iou_fused(
    const float* __restrict__ x, const _Float16* __restrict__ chs,
    const float* __restrict__ cacc,
    const _Float16* __restrict__ Wx, const _Float16* __restrict__ Wh,
    const float* __restrict__ bioux, const float* __restrict__ biouh,
    _Float16* __restrict__ c_half, float* __restrict__ h_all, int node0)
{
  __shared__ _Float16 As[2][64 * 32];
  __shared__ _Float16 Bs[2][3][CT * 32 * 32];
  const int t = threadIdx.x;
  int swzb = xcd_swz_lin(blockIdx.y * gridDim.x + blockIdx.x,
                         gridDim.x * gridDim.y);
  const int m0 = (swzb % gridDim.x) * (CT * 32);
  const int r0 = (swzb / gridDim.x) * 64;
  const int w = t >> 6, lane = t & 63;
  const int wr = (w >> 1) * 32, wc = (w & 1) * (CT * 16);
  const int fr = lane & 15, fq = (lane >> 4) * 8;

  f4_t acc[3][2][CT] = {};
  int cur = 0;
  for (int ph = 0; ph < 2; ++ph) {
    if (ph == 1 && chs == nullptr) break;
    const int K = ph ? 256 : 512;
    const _Float16* W = ph ? Wh : Wx;
    float4 va[2];
    // prologue: fill buf[cur] for k0 = 0; prefetch A regs for k0 = 32
    if (ph == 0) {
      loadA_f32<64>(x + (size_t)r0 * 512, 512, t, va);
      writeA_f16<64>(As[cur], t, va);
    } else {
      gstage<64>(chs + (size_t)r0 * 256, 256, As[cur], t);
    }
#pragma unroll
    for (int g = 0; g < 3; ++g)
      gstage<CT * 32>(W + (size_t)(g * 256 + m0) * K, K, &Bs[cur][g][0], t);
    if (ph == 0)
      loadA_f32<64>(x + (size_t)r0 * 512 + 32, 512, t, va);
    __syncthreads();

    for (int k0 = 0; k0 < K; k0 += 32) {
      int nxt = cur ^ 1;
      if (k0 + 32 < K) {
        if (ph == 0) writeA_f16<64>(As[nxt], t, va);
        else gstage<64>(chs + (size_t)r0 * 256 + k0 + 32, 256, As[nxt], t);
#pragma unroll
        for (int g = 0; g < 3; ++g)
          gstage<CT * 32>(W + (size_t)(g * 256 + m0) * K + k0 + 32, K,
                          &Bs[nxt][g][0], t);
        if (ph == 0 && k0 + 64 < K)
          loadA_f32<64>(x + (size_t)r0 * 512 + k0 + 64, 512, t, va);
      }
      h8_t a[2], b[3][CT];
#pragma unroll
      for (int rt = 0; rt < 2; ++rt) {
        int row = wr + rt * 16 + fr;
        a[rt] = *(const h8_t*)(As[cur] + row * 32 + swz(row, fq));
      }
#pragma unroll
      for (int g = 0; g < 3; ++g)
#pragma unroll
        for (int ct = 0; ct < CT; ++ct) {
          int row = wc + ct * 16 + fr;
          b[g][ct] = *(const h8_t*)(&Bs[cur][g][0] + row * 32 + swz(row, fq));
        }
#pragma unroll
      for (int g = 0; g < 3; ++g)
#pragma unroll
        for (int rt = 0; rt < 2; ++rt)
#pragma unroll
          for (int ct = 0; ct < CT; ++ct)
            acc[g][rt][ct] = __builtin_amdgcn_mfma_f32_16x16x32_f16(a[rt], b[g][ct], acc[g][rt][ct], 0, 0, 0);
      __syncthreads();
      cur = nxt;
    }
  }
#pragma unroll
  for (int rt = 0; rt < 2; ++rt)
#pragma unroll
    for (int ct = 0; ct < CT; ++ct)
#pragma unroll
      for (int i = 0; i < 4; ++i) {
        int row = wr + rt * 16 + (lane >> 4) * 4 + i;
        int col = wc + ct * 16 + (lane & 15);
        int m = m0 + col;
        size_t lrow = (size_t)(r0 + row);
        float iv = acc[0][rt][ct][i] + bioux[m] + biouh[m];
        float ov = acc[1][rt][ct][i] + bioux[256 + m] + biouh[256 + m];
        float uv = acc[2][rt][ct][i] + bioux[512 + m] + biouh[512 + m];
        float c = fsig(iv) * ftanh(uv) + (cacc ? cacc[lrow * 256 + m] : 0.f);
        float h = fsig(ov) * ftanh(c);
        size_t g = ((size_t)node0 * 256 + lrow) * 256 + m;
        h_all[g] = h;
        c_half[g] = (_Float16)c;
      }
}

extern "C" void kernel_launch(void* const* d_in, const int* in_sizes, int n_in,
                              void* d_out, int out_size, void* d_ws, size_t ws_size,
                              hipStream_t stream) {
  const float* inputs = (const float*)d_in[0];
  const float* prob   = (const float*)d_in[1];
  const float* Wioux  = (const float*)d_in[2];
  const float* bioux  = (const float*)d_in[3];
  const float* Wiouh  = (const float*)d_in[4];
  const float* biouh  = (const float*)d_in[5];
  const float* Wfx    = (const float*)d_in[6];
  const float* bfx    = (const float*)d_in[7];
  const float* Wfh    = (const float*)d_in[8];
  const float* bfh    = (const float*)d_in[9];
  float* h_out = (float*)d_out;

  char* p = (char*)d_ws;
  _Float16* c_half = (_Float16*)p; p += (size_t)585 * 65536 * 2;
  _Float16* fh     = (_Float16*)p; p += (size_t)512 * 65536 * 2;
  float*    fxb    = (float*)p;    p += (size_t)73 * 65536 * 4;
  _Float16* chs    = (_Float16*)p; p += (size_t)64 * 65536 * 2;
  float*    cacc   = (float*)p;    p += (size_t)64 * 65536 * 4;
  _Float16* Wx     = (_Float16*)p; p += (size_t)393216 * 2;
  _Float16* Wh     = (_Float16*)p; p += (size_t)196608 * 2;
  _Float16* Wfxh   = (_Float16*)p; p += (size_t)131072 * 2;
  _Float16* Wfhh   = (_Float16*)p; p += (size_t)65536 * 2;

  convert_weights<<<768, 256, 0, stream>>>(Wioux, Wiouh, Wfx, Wfh, Wx, Wh, Wfxh, Wfhh);
  fx_gemm<<<292, 256, 0, stream>>>(inputs, Wfxh, fxb);

  // leaves: nodes 73..584, rows = 512*256 = 2048 * 64
  iou_fused<4><<<dim3(2, 2048), 256, 0, stream>>>(
      inputs + (size_t)73 * 131072, nullptr, nullptr,
      Wx, Wh, bioux, biouh, c_half, h_out, 73);
  fh_gemm<<<2048, 256, 0, stream>>>(
      h_out + (size_t)73 * 65536, Wfhh, fh);

  // level 2 (s=9, L=64)
  chs_fgate<<<64 * 64, 256, 0, stream>>>(
      h_out, fh, c_half, prob, bfh, bfx, fxb, chs, cacc, 9, 73);
  iou_fused<4><<<dim3(2, 256), 256, 0, stream>>>(
      inputs + (size_t)9 * 131072, chs, cacc,
      Wx, Wh, bioux, biouh, c_half, h_out, 9);
  fh_gemm<<<256, 256, 0, stream>>>(
      h_out + (size_t)9 * 65536, Wfhh, fh);

  // level 1 (s=1, L=8): narrow tiles for tail parallelism
  chs_fgate<<<8 * 64, 256, 0, stream>>>(
      h_out, fh, c_half, prob, bfh, bfx, fxb, chs, cacc, 1, 9);
  iou_fused<2><<<dim3(4, 32), 256, 0, stream>>>(
      inputs + (size_t)1 * 131072, chs, cacc,
      Wx, Wh, bioux, biouh, c_half, h_out, 1);
  fh_gemm<<<32, 256, 0, stream>>>(
      h_out + (size_t)1 * 65536, Wfhh, fh);

  // level 0 (root)
  chs_fgate<<<64, 256, 0, stream>>>(
      h_out, fh, c_half, prob, bfh, bfx, fxb, chs, cacc, 0, 1);
  iou_fused<2><<<dim3(4, 4), 256, 0, stream>>>(
      inputs, chs, cacc,
      Wx, Wh, bioux, biouh, c_half, h_out, 0);
}

// Round 13
// 850.952 us; speedup vs baseline: 1.1935x; 1.1935x over previous
//
#include <hip/hip_runtime.h>
#include <math.h>

typedef _Float16 h8_t __attribute__((ext_vector_type(8)));
typedef _Float16 h4_t __attribute__((ext_vector_type(4)));
typedef float f4_t __attribute__((ext_vector_type(4)));

// LDS tiles: [R][32] halfs (64 B rows) with a 16B-slot XOR swizzle:
// logical chunk g (0..3) of row r is stored at slot s = g ^ ((r>>1)&3).
// Verified on HW (round 11): SQ_LDS_BANK_CONFLICT 1.47e7 -> 0, bit-exact.
// SINGLE-buffered K-loop: round-11 measured that double-buffering (2x LDS,
// 57 KB) halves occupancy (21%->12%) and costs 1.5x — inter-block overlap
// at 28 KB LDS hides the barrier drain better than intra-block dbuf.

__device__ __forceinline__ int swz(int row, int fq) {
  return fq ^ (((row >> 1) & 3) << 3);   // fq in halfs (0,8,16,24)
}

// fast sigmoid / tanh using native v_exp_f32 + v_rcp_f32.
__device__ __forceinline__ float fsig(float x) {
  return __builtin_amdgcn_rcpf(1.f + __expf(-x));
}
__device__ __forceinline__ float ftanh(float x) {
  float e = __expf(-2.f * fabsf(x));
  float t = (1.f - e) * __builtin_amdgcn_rcpf(1.f + e);
  return copysignf(t, x);
}

// XCD-aware bijective block swizzle (T1).
__device__ __forceinline__ int xcd_swz_lin(int lin, int nwg) {
  if (nwg & 7) return lin;
  int cpx = nwg >> 3;
  return (lin & 7) * cpx + (lin >> 3);
}

// async global->LDS, 16 B per lane (dest = wave-uniform base + lane*16).
__device__ __forceinline__ void gload16(const _Float16* g, _Float16* l) {
  __builtin_amdgcn_global_load_lds(
      (const __attribute__((address_space(1))) void*)g,
      (__attribute__((address_space(3))) void*)l, 16, 0, 0);
}

// stage R rows x 32 halfs from f16 source into swizzled LDS [R][32].
// LDS dest linear (idx*16 B); source chunk g = slot ^ ((row>>1)&3).
template <int R>
__device__ __forceinline__ void gstage(const _Float16* __restrict__ src, int ld,
                                       _Float16* __restrict__ dst, int t) {
#pragma unroll
  for (int it = 0; it < R / 64; ++it) {
    int idx = t + it * 256;       // 0..R*4-1
    int row = idx >> 2;           // 0..R-1
    int sl  = idx & 3;            // phys slot
    int kq  = (sl ^ ((row >> 1) & 3)) << 3;   // logical chunk, halfs
    gload16(src + (size_t)row * ld + kq, dst + (size_t)idx * 8);
  }
}

// T14 reg-staged fp32 A-path: loadA issues float4 loads to regs (placed
// after barrier2/before MFMA so they complete under the MFMA window);
// writeA cvt+ds_write into swizzled LDS (conflict-free).
template <int R>
__device__ __forceinline__ void loadA_f32(const float* __restrict__ src, int ld,
                                          int t, float4* v) {
#pragma unroll
  for (int it = 0; it < R / 32; ++it) {
    int idx = t + it * 256;       // 0..R*8-1
    int row = idx >> 3;           // 0..R-1
    int kg  = (idx & 7) << 2;     // 0,4,..,28
    v[it] = *(const float4*)(src + (size_t)row * ld + kg);
  }
}
template <int R>
__device__ __forceinline__ void writeA_f16(_Float16* __restrict__ dst, int t,
                                           const float4* v) {
#pragma unroll
  for (int it = 0; it < R / 32; ++it) {
    int idx = t + it * 256;
    int row = idx >> 3;
    int c   = idx & 7;            // 8-B chunk index
    int g   = c >> 1, h = c & 1;
    int sl  = g ^ ((row >> 1) & 3);
    h4_t hv = {(_Float16)v[it].x, (_Float16)v[it].y,
               (_Float16)v[it].z, (_Float16)v[it].w};
    *(h4_t*)(dst + row * 32 + sl * 8 + h * 4) = hv;
  }
}

// Convert the 4 weight matrices fp32 -> f16 (one launch)
__global__ __launch_bounds__(256) void convert_weights(
    const float* __restrict__ Wioux, const float* __restrict__ Wiouh,
    const float* __restrict__ Wfx, const float* __restrict__ Wfh,
    _Float16* __restrict__ Wx, _Float16* __restrict__ Wh,
    _Float16* __restrict__ Wfxh, _Float16* __restrict__ Wfhh)
{
  int i4 = (blockIdx.x * 256 + threadIdx.x) * 4;   // < 786432
  const float* src; _Float16* dst; int off;
  if (i4 < 393216)      { src = Wioux; dst = Wx;   off = i4; }
  else if (i4 < 589824) { src = Wiouh; dst = Wh;   off = i4 - 393216; }
  else if (i4 < 720896) { src = Wfx;   dst = Wfxh; off = i4 - 589824; }
  else                  { src = Wfh;   dst = Wfhh; off = i4 - 720896; }
  float4 v = *(const float4*)(src + off);
  h4_t h = {(_Float16)v.x, (_Float16)v.y, (_Float16)v.z, (_Float16)v.w};
  *(h4_t*)(dst + off) = h;
}

// fx = x @ Wfx.T (rows = 73*256), fp32 out. 64-row x 256-col tile,
// single-buffer, T14 post-barrier2 A prefetch, swizzled LDS.
__global__ __launch_bounds__(256) void fx_gemm(
    const float* __restrict__ x, const _Float16* __restrict__ Wfx,
    float* __restrict__ out)
{
  __shared__ _Float16 As[64 * 32];
  __shared__ _Float16 Bs[256 * 32];
  const int t = threadIdx.x;
  int swzb = xcd_swz_lin(blockIdx.x, gridDim.x);
  const int r0 = swzb * 64;
  const int w = t >> 6, lane = t & 63;
  const int wr = (w >> 1) * 32, wc = (w & 1) * 128;
  const int fr = lane & 15, fq = (lane >> 4) * 8;
  f4_t acc[2][8] = {};
  float4 va[2], vn[2];
  loadA_f32<64>(x + (size_t)r0 * 512, 512, t, va);
  for (int k0 = 0; k0 < 512; k0 += 32) {
    __syncthreads();
    writeA_f16<64>(As, t, va);
    gstage<256>(Wfx + (size_t)k0, 512, Bs, t);
    __syncthreads();
    if (k0 + 32 < 512)
      loadA_f32<64>(x + (size_t)r0 * 512 + k0 + 32, 512, t, vn);
    h8_t a[2], b[8];
#pragma unroll
    for (int rt = 0; rt < 2; ++rt) {
      int row = wr + rt * 16 + fr;
      a[rt] = *(const h8_t*)(As + row * 32 + swz(row, fq));
    }
#pragma unroll
    for (int ct = 0; ct < 8; ++ct) {
      int row = wc + ct * 16 + fr;
      b[ct] = *(const h8_t*)(Bs + row * 32 + swz(row, fq));
    }
#pragma unroll
    for (int rt = 0; rt < 2; ++rt)
#pragma unroll
      for (int ct = 0; ct < 8; ++ct)
        acc[rt][ct] = __builtin_amdgcn_mfma_f32_16x16x32_f16(a[rt], b[ct], acc[rt][ct], 0, 0, 0);
    if (k0 + 32 < 512) { va[0] = vn[0]; va[1] = vn[1]; }
  }
#pragma unroll
  for (int rt = 0; rt < 2; ++rt)
#pragma unroll
    for (int ct = 0; ct < 8; ++ct)
#pragma unroll
      for (int i = 0; i < 4; ++i) {
        int row = wr + rt * 16 + (lane >> 4) * 4 + i;
        int col = wc + ct * 16 + (lane & 15);
        out[(size_t)(r0 + row) * 256 + col] = acc[rt][ct][i];
      }
}

// fh = h @ Wfh.T (rows = L*256), f16 out. Same structure, K=256.
__global__ __launch_bounds__(256) void fh_gemm(
    const float* __restrict__ h_src, const _Float16* __restrict__ Wfh,
    _Float16* __restrict__ out)
{
  __shared__ _Float16 As[64 * 32];
  __shared__ _Float16 Bs[256 * 32];
  const int t = threadIdx.x;
  int swzb = xcd_swz_lin(blockIdx.x, gridDim.x);
  const int r0 = swzb * 64;
  const int w = t >> 6, lane = t & 63;
  const int wr = (w >> 1) * 32, wc = (w & 1) * 128;
  const int fr = lane & 15, fq = (lane >> 4) * 8;
  f4_t acc[2][8] = {};
  float4 va[2], vn[2];
  loadA_f32<64>(h_src + (size_t)r0 * 256, 256, t, va);
  for (int k0 = 0; k0 < 256; k0 += 32) {
    __syncthreads();
    writeA_f16<64>(As, t, va);
    gstage<256>(Wfh + (size_t)k0, 256, Bs, t);
    __syncthreads();
    if (k0 + 32 < 256)
      loadA_f32<64>(h_src + (size_t)r0 * 256 + k0 + 32, 256, t, vn);
    h8_t a[2], b[8];
#pragma unroll
    for (int rt = 0; rt < 2; ++rt) {
      int row = wr + rt * 16 + fr;
      a[rt] = *(const h8_t*)(As + row * 32 + swz(row, fq));
    }
#pragma unroll
    for (int ct = 0; ct < 8; ++ct) {
      int row = wc + ct * 16 + fr;
      b[ct] = *(const h8_t*)(Bs + row * 32 + swz(row, fq));
    }
#pragma unroll
    for (int rt = 0; rt < 2; ++rt)
#pragma unroll
      for (int ct = 0; ct < 8; ++ct)
        acc[rt][ct] = __builtin_amdgcn_mfma_f32_16x16x32_f16(a[rt], b[ct], acc[rt][ct], 0, 0, 0);
    if (k0 + 32 < 256) { va[0] = vn[0]; va[1] = vn[1]; }
  }
#pragma unroll
  for (int rt = 0; rt < 2; ++rt)
#pragma unroll
    for (int ct = 0; ct < 8; ++ct)
#pragma unroll
      for (int i = 0; i < 4; ++i) {
        int row = wr + rt * 16 + (lane >> 4) * 4 + i;
        int col = wc + ct * 16 + (lane & 15);
        out[(size_t)(r0 + row) * 256 + col] = (_Float16)acc[rt][ct][i];
      }
}

// Fused: chs = f16(sum_j w_j h[child_j]) AND
// cacc = sum_j sigmoid(w_j*fh[child_j] + bfh + bfx + fx) * w_j * c[child_j]
__global__ __launch_bounds__(256) void chs_fgate(
    const float* __restrict__ h_all, const _Float16* __restrict__ fh,
    const _Float16* __restrict__ c_half, const float* __restrict__ prob,
    const float* __restrict__ bfh, const float* __restrict__ bfx,
    const float* __restrict__ fxb, _Float16* __restrict__ chs,
    float* __restrict__ cacc, int s, int cs)
{
  int blk = xcd_swz_lin(blockIdx.x, gridDim.x);
  int idx = blk * 256 + threadIdx.x;   // over L*16384
  int m = (idx & 63) << 2;
  int b = (idx >> 6) & 255;
  int nl = idx >> 14;
  int node = s + nl;
  float4 vfx = *(const float4*)(fxb + ((size_t)node * 256 + b) * 256 + m);
  float4 vbh = *(const float4*)(bfh + m);
  float4 vbx = *(const float4*)(bfx + m);
  float b0 = vfx.x + vbh.x + vbx.x;
  float b1 = vfx.y + vbh.y + vbx.y;
  float b2 = vfx.z + vbh.z + vbx.z;
  float b3 = vfx.w + vbh.w + vbx.w;
  float4 hacc = {0.f, 0.f, 0.f, 0.f};
  float4 cc = {0.f, 0.f, 0.f, 0.f};
#pragma unroll
  for (int j = 0; j < 8; ++j) {
    int child = node * 8 + 1 + j;
    float wv = prob[node * 585 + child];
    float4 hv = *(const float4*)(h_all + (size_t)child * 65536 + b * 256 + m);
    hacc.x += wv * hv.x; hacc.y += wv * hv.y;
    hacc.z += wv * hv.z; hacc.w += wv * hv.w;
    h4_t fv = *(const h4_t*)(fh + (size_t)(child - cs) * 65536 + b * 256 + m);
    h4_t cv = *(const h4_t*)(c_half + (size_t)child * 65536 + b * 256 + m);
    cc.x += wv * (float)cv[0] * fsig(wv * (float)fv[0] + b0);
    cc.y += wv * (float)cv[1] * fsig(wv * (float)fv[1] + b1);
    cc.z += wv * (float)cv[2] * fsig(wv * (float)fv[2] + b2);
    cc.w += wv * (float)cv[3] * fsig(wv * (float)fv[3] + b3);
  }
  h4_t hc = {(_Float16)hacc.x, (_Float16)hacc.y, (_Float16)hacc.z, (_Float16)hacc.w};
  *(h4_t*)(chs + (size_t)nl * 65536 + b * 256 + m) = hc;
  *(float4*)(cacc + ((size_t)nl * 256 + b) * 256 + m) = cc;
}

// Fused iou GEMM + pointwise, 64 rows x (CT*32) m-cols x 3 gates.
// Single-buffer K-loop + T14 post-barrier2 A prefetch + swizzled LDS.
template <int CT>
__global__ __launch_bounds__(256) void iou_fused(
    const float* __restrict__ x, const _Float16* __restrict__ chs,
    const float* __restrict__ cacc,
    const _Float16* __restrict__ Wx, const _Float16* __restrict__ Wh,
    const float* __restrict__ bioux, const float* __restrict__ biouh,
    _Float16* __restrict__ c_half, float* __restrict__ h_all, int node0)
{
  __shared__ _Float16 As[64 * 32];
  __shared__ _Float16 Bs[3][CT * 32 * 32];
  const int t = threadIdx.x;
  int swzb = xcd_swz_lin(blockIdx.y * gridDim.x + blockIdx.x,
                         gridDim.x * gridDim.y);
  const int m0 = (swzb % gridDim.x) * (CT * 32);
  const int r0 = (swzb / gridDim.x) * 64;
  const int w = t >> 6, lane = t & 63;
  const int wr = (w >> 1) * 32, wc = (w & 1) * (CT * 16);
  const int fr = lane & 15, fq = (lane >> 4) * 8;

  f4_t acc[3][2][CT] = {};
  for (int ph = 0; ph < 2; ++ph) {
    if (ph == 1 && chs == nullptr) break;
    const int K = ph ? 256 : 512;
    const _Float16* W = ph ? Wh : Wx;
    float4 va[2], vn[2];
    if (ph == 0) loadA_f32<64>(x + (size_t)r0 * 512, 512, t, va);
    for (int k0 = 0; k0 < K; k0 += 32) {
      __syncthreads();
      if (ph == 0) writeA_f16<64>(As, t, va);
      else         gstage<64>(chs + (size_t)r0 * 256 + k0, 256, As, t);
#pragma unroll
      for (int g = 0; g < 3; ++g)
        gstage<CT * 32>(W + (size_t)(g * 256 + m0) * K + k0, K, &Bs[g][0], t);
      __syncthreads();
      // issue next A-loads here: they complete under the MFMA cluster
      if (ph == 0 && k0 + 32 < K)
        loadA_f32<64>(x + (size_t)r0 * 512 + k0 + 32, 512, t, vn);
      h8_t a[2], b[3][CT];
#pragma unroll
      for (int rt = 0; rt < 2; ++rt) {
        int row = wr + rt * 16 + fr;
        a[rt] = *(const h8_t*)(As + row * 32 + swz(row, fq));
      }
#pragma unroll
      for (int g = 0; g < 3; ++g)
#pragma unroll
        for (int ct = 0; ct < CT; ++ct) {
          int row = wc + ct * 16 + fr;
          b[g][ct] = *(const h8_t*)(&Bs[g][0] + row * 32 + swz(row, fq));
        }
#pragma unroll
      for (int g = 0; g < 3; ++g)
#pragma unroll
        for (int rt = 0; rt < 2; ++rt)
#pragma unroll
          for (int ct = 0; ct < CT; ++ct)
            acc[g][rt][ct] = __builtin_amdgcn_mfma_f32_16x16x32_f16(a[rt], b[g][ct], acc[g][rt][ct], 0, 0, 0);
      if (ph == 0 && k0 + 32 < K) { va[0] = vn[0]; va[1] = vn[1]; }
    }
  }
#pragma unroll
  for (int rt = 0; rt < 2; ++rt)
#pragma unroll
    for (int ct = 0; ct < CT; ++ct)
#pragma unroll
      for (int i = 0; i < 4; ++i) {
        int row = wr + rt * 16 + (lane >> 4) * 4 + i;
        int col = wc + ct * 16 + (lane & 15);
        int m = m0 + col;
        size_t lrow = (size_t)(r0 + row);
        float iv = acc[0][rt][ct][i] + bioux[m] + biouh[m];
        float ov = acc[1][rt][ct][i] + bioux[256 + m] + biouh[256 + m];
        float uv = acc[2][rt][ct][i] + bioux[512 + m] + biouh[512 + m];
        float c = fsig(iv) * ftanh(uv) + (cacc ? cacc[lrow * 256 + m] : 0.f);
        float h = fsig(ov) * ftanh(c);
        size_t g = ((size_t)node0 * 256 + lrow) * 256 + m;
        h_all[g] = h;
        c_half[g] = (_Float16)c;
      }
}

extern "C" void kernel_launch(void* const* d_in, const int* in_sizes, int n_in,
                              void* d_out, int out_size, void* d_ws, size_t ws_size,
                              hipStream_t stream) {
  const float* inputs = (const float*)d_in[0];
  const float* prob   = (const float*)d_in[1];
  const float* Wioux  = (const float*)d_in[2];
  const float* bioux  = (const float*)d_in[3];
  const float* Wiouh  = (const float*)d_in[4];
  const float* biouh  = (const float*)d_in[5];
  const float* Wfx    = (const float*)d_in[6];
  const float* bfx    = (const float*)d_in[7];
  const float* Wfh    = (const float*)d_in[8];
  const float* bfh    = (const float*)d_in[9];
  float* h_out = (float*)d_out;

  char* p = (char*)d_ws;
  _Float16* c_half = (_Float16*)p; p += (size_t)585 * 65536 * 2;
  _Float16* fh     = (_Float16*)p; p += (size_t)512 * 65536 * 2;
  float*    fxb    = (float*)p;    p += (size_t)73 * 65536 * 4;
  _Float16* chs    = (_Float16*)p; p += (size_t)64 * 65536 * 2;
  float*    cacc   = (float*)p;    p += (size_t)64 * 65536 * 4;
  _Float16* Wx     = (_Float16*)p; p += (size_t)393216 * 2;
  _Float16* Wh     = (_Float16*)p; p += (size_t)196608 * 2;
  _Float16* Wfxh   = (_Float16*)p; p += (size_t)131072 * 2;
  _Float16* Wfhh   = (_Float16*)p; p += (size_t)65536 * 2;

  convert_weights<<<768, 256, 0, stream>>>(Wioux, Wiouh, Wfx, Wfh, Wx, Wh, Wfxh, Wfhh);
  fx_gemm<<<292, 256, 0, stream>>>(inputs, Wfxh, fxb);

  // leaves: nodes 73..584, rows = 512*256 = 2048 * 64
  iou_fused<4><<<dim3(2, 2048), 256, 0, stream>>>(
      inputs + (size_t)73 * 131072, nullptr, nullptr,
      Wx, Wh, bioux, biouh, c_half, h_out, 73);
  fh_gemm<<<2048, 256, 0, stream>>>(
      h_out + (size_t)73 * 65536, Wfhh, fh);

  // level 2 (s=9, L=64)
  chs_fgate<<<64 * 64, 256, 0, stream>>>(
      h_out, fh, c_half, prob, bfh, bfx, fxb, chs, cacc, 9, 73);
  iou_fused<4><<<dim3(2, 256), 256, 0, stream>>>(
      inputs + (size_t)9 * 131072, chs, cacc,
      Wx, Wh, bioux, biouh, c_half, h_out, 9);
  fh_gemm<<<256, 256, 0, stream>>>(
      h_out + (size_t)9 * 65536, Wfhh, fh);

  // level 1 (s=1, L=8): narrow tiles for tail parallelism
  chs_fgate<<<8 * 64, 256, 0, stream>>>(
      h_out, fh, c_half, prob, bfh, bfx, fxb, chs, cacc, 1, 9);
  iou_fused<2><<<dim3(4, 32), 256, 0, stream>>>(
      inputs + (size_t)1 * 131072, chs, cacc,
      Wx, Wh, bioux, biouh, c_half, h_out, 1);
  fh_gemm<<<32, 256, 0, stream>>>(
      h_out + (size_t)1 * 65536, Wfhh, fh);

  // level 0 (root)
  chs_fgate<<<64, 256, 0, stream>>>(
      h_out, fh, c_half, prob, bfh, bfx, fxb, chs, cacc, 0, 1);
  iou_fused<2><<<dim3(4, 4), 256, 0, stream>>>(
      inputs, chs, cacc,
      Wx, Wh, bioux, biouh, c_half, h_out, 0);
}